// Round 1
// baseline (1054.210 us; speedup 1.0000x reference)
//
#include <hip/hip_runtime.h>
#include <stdint.h>

#define BB 1024
#define NN 400
#define EE 128
#define DD 128

typedef float f32x4 __attribute__((ext_vector_type(4)));
typedef short bf16x8 __attribute__((ext_vector_type(8)));
typedef short bf16x4 __attribute__((ext_vector_type(4)));

__device__ __forceinline__ short f2bf(float f) {
    uint32_t u = __builtin_bit_cast(uint32_t, f);
    u += 0x7fffu + ((u >> 16) & 1u);
    return (short)(u >> 16);
}

__device__ __forceinline__ bf16x8 cvt8(const f32x4 a, const f32x4 b) {
    bf16x8 r;
    r[0] = f2bf(a[0]); r[1] = f2bf(a[1]); r[2] = f2bf(a[2]); r[3] = f2bf(a[3]);
    r[4] = f2bf(b[0]); r[5] = f2bf(b[1]); r[6] = f2bf(b[2]); r[7] = f2bf(b[3]);
    return r;
}

// K1: per (b, E-half): P' = [S_half; T_half] @ G  (128x400 @ 400x128), then
// h = Pa @ W1a^T + Pb @ W1b^T + b1  (64x128), write h, accumulate BN1 stats.
__global__ __launch_bounds__(256, 3)
void k1_gemm(const float* __restrict__ gout, const float* __restrict__ ss,
             const float* __restrict__ es, const float* __restrict__ W1,
             const float* __restrict__ b1, float* __restrict__ h,
             float* __restrict__ stats)
{
    __shared__ short As[128 * 40];   // A' tile (128 rows x 32 k), stride 40
    __shared__ short Gs[128 * 40];   // G tile transposed: [d][k], stride 40
    __shared__ short Ps[128 * 128];  // P' bf16, XOR-swizzled 8-elem blocks

    const int bid = blockIdx.x;
    const int b   = bid >> 1;
    const int e0  = (bid & 1) * 64;
    const int t   = threadIdx.x;
    const int w   = t >> 6;
    const int l15 = t & 15;
    const int l4  = (t >> 4) & 3;

    f32x4 acc[2][8];
#pragma unroll
    for (int i = 0; i < 2; ++i)
#pragma unroll
        for (int j = 0; j < 8; ++j) acc[i][j] = f32x4{0.f, 0.f, 0.f, 0.f};

    f32x4 ar[4], gr[4];
    const int arow = t >> 3;        // 0..31, +32p
    const int acol = (t & 7) * 4;   // k-offset within tile
    const int gkr  = t >> 5;        // 0..7, +8p
    const int gcol = (t & 31) * 4;  // d column

    auto load_tiles = [&](int k0) {
#pragma unroll
        for (int p = 0; p < 4; ++p) {
            int row = arow + 32 * p;
            int col = k0 + acol;
            const float* src = (row < 64)
                ? ss + (size_t)(b * EE + e0 + row) * NN + col
                : es + (size_t)(b * EE + e0 + row - 64) * NN + col;
            ar[p] = (col < NN) ? *(const f32x4*)src : f32x4{0.f, 0.f, 0.f, 0.f};
        }
#pragma unroll
        for (int p = 0; p < 4; ++p) {
            int kr = gkr + 8 * p;
            const float* src = gout + (size_t)(b * NN + k0 + kr) * DD + gcol;
            gr[p] = (k0 + kr < NN) ? *(const f32x4*)src : f32x4{0.f, 0.f, 0.f, 0.f};
        }
    };

    auto store_tiles = [&]() {
#pragma unroll
        for (int p = 0; p < 4; ++p) {
            int row = arow + 32 * p;
            bf16x4 v;
            v[0] = f2bf(ar[p][0]); v[1] = f2bf(ar[p][1]);
            v[2] = f2bf(ar[p][2]); v[3] = f2bf(ar[p][3]);
            *(bf16x4*)&As[row * 40 + acol] = v;
        }
#pragma unroll
        for (int p = 0; p < 4; ++p) {
            int kr = gkr + 8 * p;
            Gs[(gcol + 0) * 40 + kr] = f2bf(gr[p][0]);
            Gs[(gcol + 1) * 40 + kr] = f2bf(gr[p][1]);
            Gs[(gcol + 2) * 40 + kr] = f2bf(gr[p][2]);
            Gs[(gcol + 3) * 40 + kr] = f2bf(gr[p][3]);
        }
    };

    load_tiles(0);
    const int NK = (NN + 31) / 32;  // 13
    for (int step = 0; step < NK; ++step) {
        store_tiles();
        __syncthreads();
        if (step + 1 < NK) load_tiles((step + 1) * 32);
        bf16x8 af[2];
#pragma unroll
        for (int rf = 0; rf < 2; ++rf) {
            int row = w * 32 + rf * 16 + l15;
            af[rf] = *(const bf16x8*)&As[row * 40 + l4 * 8];
        }
#pragma unroll
        for (int cf = 0; cf < 8; ++cf) {
            int col = cf * 16 + l15;
            bf16x8 bfr = *(const bf16x8*)&Gs[col * 40 + l4 * 8];
            acc[0][cf] = __builtin_amdgcn_mfma_f32_16x16x32_bf16(af[0], bfr, acc[0][cf], 0, 0, 0);
            acc[1][cf] = __builtin_amdgcn_mfma_f32_16x16x32_bf16(af[1], bfr, acc[1][cf], 0, 0, 0);
        }
        __syncthreads();
    }

    // P' -> LDS bf16, swizzled: off = row*128 + ((col>>3 ^ row&7)*8) + col&7
#pragma unroll
    for (int rf = 0; rf < 2; ++rf)
#pragma unroll
        for (int cf = 0; cf < 8; ++cf)
#pragma unroll
            for (int r = 0; r < 4; ++r) {
                int row = w * 32 + rf * 16 + l4 * 4 + r;
                int col = cf * 16 + l15;
                int off = row * 128 + (((col >> 3) ^ (row & 7)) * 8) + (col & 7);
                Ps[off] = f2bf(acc[rf][cf][r]);
            }
    __syncthreads();

    // Stage 2: h(64x128) = X(64x256) @ W1^T, X from Ps
    f32x4 hacc[4][2];
#pragma unroll
    for (int i = 0; i < 4; ++i) {
        hacc[i][0] = f32x4{0.f, 0.f, 0.f, 0.f};
        hacc[i][1] = f32x4{0.f, 0.f, 0.f, 0.f};
    }
#pragma unroll
    for (int kf = 0; kf < 8; ++kf) {
        const int k0   = kf * 32;
        const int roff = (kf >= 4) ? 64 : 0;
        const int cb   = ((k0 & 127) >> 3) + l4;
        bf16x8 af[4];
#pragma unroll
        for (int rf = 0; rf < 4; ++rf) {
            int row = roff + rf * 16 + l15;
            af[rf] = *(const bf16x8*)&Ps[row * 128 + ((cb ^ (row & 7)) * 8)];
        }
#pragma unroll
        for (int cf = 0; cf < 2; ++cf) {
            int j = w * 32 + cf * 16 + l15;
            const float* wp = W1 + (size_t)j * 256 + k0 + l4 * 8;
            bf16x8 bfr = cvt8(*(const f32x4*)wp, *(const f32x4*)(wp + 4));
#pragma unroll
            for (int rf = 0; rf < 4; ++rf)
                hacc[rf][cf] = __builtin_amdgcn_mfma_f32_16x16x32_bf16(af[rf], bfr, hacc[rf][cf], 0, 0, 0);
        }
    }

    // epilogue: bias, store h, BN1 stats atomics
    const float bj0 = b1[w * 32 + l15];
    const float bj1 = b1[w * 32 + 16 + l15];
    const int j0 = w * 32 + l15;
#pragma unroll
    for (int rf = 0; rf < 4; ++rf) {
        f32x4 v0 = hacc[rf][0] + bj0;
        f32x4 v1 = hacc[rf][1] + bj1;
        int ebase = e0 + rf * 16 + l4 * 4;
#pragma unroll
        for (int r = 0; r < 4; ++r) {
            float* hp = h + (size_t)(b * EE + ebase + r) * DD;
            hp[j0]      = v0[r];
            hp[j0 + 16] = v1[r];
            float s = v0[r] + v1[r];
            float q = v0[r] * v0[r] + v1[r] * v1[r];
            s += __shfl_xor(s, 1); s += __shfl_xor(s, 2); s += __shfl_xor(s, 4); s += __shfl_xor(s, 8);
            q += __shfl_xor(q, 1); q += __shfl_xor(q, 2); q += __shfl_xor(q, 4); q += __shfl_xor(q, 8);
            if (l15 == 0) {
                atomicAdd(&stats[ebase + r], s);
                atomicAdd(&stats[128 + ebase + r], q);
            }
        }
    }
}

// K3: per b: finalize BN1, normalize+relu h -> bf16 LDS, h2 = X @ W2^T + b2,
// write h2 to d_out (scratch), accumulate BN2 stats.
__global__ __launch_bounds__(256, 3)
void k3_gemm(const float* __restrict__ h, const float* __restrict__ W2,
             const float* __restrict__ b2, const float* __restrict__ g1,
             const float* __restrict__ bt1, float* __restrict__ out,
             float* __restrict__ stats)
{
    __shared__ short Xs[128 * 128];
    __shared__ float sc[128];
    __shared__ float sh[128];
    const int b   = blockIdx.x;
    const int t   = threadIdx.x;
    const int w   = t >> 6;
    const int l15 = t & 15;
    const int l4  = (t >> 4) & 3;

    if (t < 128) {
        const float inv_n = 1.0f / (1024.0f * 128.0f);
        float m    = stats[t] * inv_n;
        float var  = stats[128 + t] * inv_n - m * m;
        float rstd = rsqrtf(var + 1e-5f);
        float s    = rstd * g1[t];
        sc[t] = s;
        sh[t] = bt1[t] - m * s;
    }
    __syncthreads();

    {
        const int eb = t >> 5;
        const int c4 = t & 31;
#pragma unroll
        for (int p = 0; p < 16; ++p) {
            int e = eb + 8 * p;
            f32x4 v = *(const f32x4*)(h + (size_t)(b * EE + e) * DD + c4 * 4);
            float s = sc[e], s0 = sh[e];
            bf16x4 o;
#pragma unroll
            for (int i = 0; i < 4; ++i)
                o[i] = f2bf(fmaxf(fmaf(v[i], s, s0), 0.0f));
            int col = c4 * 4;
            int off = e * 128 + (((col >> 3) ^ (e & 7)) * 8) + (col & 7);
            *(bf16x4*)&Xs[off] = o;
        }
    }
    __syncthreads();

    f32x4 acc[8][2];
#pragma unroll
    for (int i = 0; i < 8; ++i) {
        acc[i][0] = f32x4{0.f, 0.f, 0.f, 0.f};
        acc[i][1] = f32x4{0.f, 0.f, 0.f, 0.f};
    }
#pragma unroll
    for (int kf = 0; kf < 4; ++kf) {
        const int k0 = kf * 32;
        const int cb = (k0 >> 3) + l4;
        bf16x8 af[8];
#pragma unroll
        for (int rf = 0; rf < 8; ++rf) {
            int row = rf * 16 + l15;
            af[rf] = *(const bf16x8*)&Xs[row * 128 + ((cb ^ (row & 7)) * 8)];
        }
#pragma unroll
        for (int cf = 0; cf < 2; ++cf) {
            int j = w * 32 + cf * 16 + l15;
            const float* wp = W2 + (size_t)j * 128 + k0 + l4 * 8;
            bf16x8 bfr = cvt8(*(const f32x4*)wp, *(const f32x4*)(wp + 4));
#pragma unroll
            for (int rf = 0; rf < 8; ++rf)
                acc[rf][cf] = __builtin_amdgcn_mfma_f32_16x16x32_bf16(af[rf], bfr, acc[rf][cf], 0, 0, 0);
        }
    }

    const float bj0 = b2[w * 32 + l15];
    const float bj1 = b2[w * 32 + 16 + l15];
    const int j0 = w * 32 + l15;
#pragma unroll
    for (int rf = 0; rf < 8; ++rf) {
        f32x4 v0 = acc[rf][0] + bj0;
        f32x4 v1 = acc[rf][1] + bj1;
        int ebase = rf * 16 + l4 * 4;
#pragma unroll
        for (int r = 0; r < 4; ++r) {
            float* op = out + (size_t)(b * EE + ebase + r) * DD;
            op[j0]      = v0[r];
            op[j0 + 16] = v1[r];
            float s = v0[r] + v1[r];
            float q = v0[r] * v0[r] + v1[r] * v1[r];
            s += __shfl_xor(s, 1); s += __shfl_xor(s, 2); s += __shfl_xor(s, 4); s += __shfl_xor(s, 8);
            q += __shfl_xor(q, 1); q += __shfl_xor(q, 2); q += __shfl_xor(q, 4); q += __shfl_xor(q, 8);
            if (l15 == 0) {
                atomicAdd(&stats[256 + ebase + r], s);
                atomicAdd(&stats[384 + ebase + r], q);
            }
        }
    }
}

// K5: finalize BN2, out = relu(eout + h2*scale + shift), in-place on d_out.
__global__ __launch_bounds__(256)
void k5_final(const float* __restrict__ eout, const float* __restrict__ g2,
              const float* __restrict__ bt2, float* __restrict__ io,
              const float* __restrict__ stats)
{
    __shared__ float sc[128];
    __shared__ float sh[128];
    const int t = threadIdx.x;
    if (t < 128) {
        const float inv_n = 1.0f / (1024.0f * 128.0f);
        float m    = stats[256 + t] * inv_n;
        float var  = stats[384 + t] * inv_n - m * m;
        float rstd = rsqrtf(var + 1e-5f);
        float s    = rstd * g2[t];
        sc[t] = s;
        sh[t] = bt2[t] - m * s;
    }
    __syncthreads();

    const int total4 = BB * EE * DD / 4;
    for (int i4 = blockIdx.x * blockDim.x + t; i4 < total4; i4 += gridDim.x * blockDim.x) {
        int e = (i4 >> 5) & 127;
        f32x4 v = *(f32x4*)(io + (size_t)i4 * 4);
        f32x4 u = *(const f32x4*)(eout + (size_t)i4 * 4);
        float s = sc[e], s0 = sh[e];
        f32x4 o;
#pragma unroll
        for (int i = 0; i < 4; ++i)
            o[i] = fmaxf(u[i] + fmaf(v[i], s, s0), 0.0f);
        *(f32x4*)(io + (size_t)i4 * 4) = o;
    }
}

extern "C" void kernel_launch(void* const* d_in, const int* in_sizes, int n_in,
                              void* d_out, int out_size, void* d_ws, size_t ws_size,
                              hipStream_t stream)
{
    const float* gout  = (const float*)d_in[0];
    const float* eout  = (const float*)d_in[1];
    const float* ss    = (const float*)d_in[2];
    const float* es    = (const float*)d_in[3];
    const float* W1    = (const float*)d_in[4];
    const float* b1    = (const float*)d_in[5];
    const float* W2    = (const float*)d_in[6];
    const float* b2    = (const float*)d_in[7];
    const float* g1    = (const float*)d_in[8];
    const float* bt1   = (const float*)d_in[9];
    const float* g2    = (const float*)d_in[10];
    const float* bt2   = (const float*)d_in[11];

    float* stats = (float*)d_ws;
    float* h     = (float*)((char*)d_ws + 4096);
    float* out   = (float*)d_out;

    hipMemsetAsync(stats, 0, 512 * sizeof(float), stream);
    k1_gemm<<<dim3(BB * 2), dim3(256), 0, stream>>>(gout, ss, es, W1, b1, h, stats);
    k3_gemm<<<dim3(BB), dim3(256), 0, stream>>>(h, W2, b2, g1, bt1, out, stats);
    k5_final<<<dim3(2048), dim3(256), 0, stream>>>(eout, g2, bt2, out, stats);
}

// Round 2
// 269.192 us; speedup vs baseline: 3.9162x; 3.9162x over previous
//
#include <hip/hip_runtime.h>
#include <stdint.h>

#define BB 1024
#define NN 400
#define EE 128
#define DD 128
#define NSLOT 64

typedef float f32x4 __attribute__((ext_vector_type(4)));
typedef short bf16x8 __attribute__((ext_vector_type(8)));
typedef short bf16x4 __attribute__((ext_vector_type(4)));

__device__ __forceinline__ short f2bf(float f) {
    uint32_t u = __builtin_bit_cast(uint32_t, f);
    u += 0x7fffu + ((u >> 16) & 1u);
    return (short)(u >> 16);
}

__device__ __forceinline__ bf16x8 cvt8(const f32x4 a, const f32x4 b) {
    bf16x8 r;
    r[0] = f2bf(a[0]); r[1] = f2bf(a[1]); r[2] = f2bf(a[2]); r[3] = f2bf(a[3]);
    r[4] = f2bf(b[0]); r[5] = f2bf(b[1]); r[6] = f2bf(b[2]); r[7] = f2bf(b[3]);
    return r;
}

// K1: per (b, E-half): P' = [S_half; T_half] @ G  (128x400 @ 400x128), then
// h = Pa @ W1a^T + Pb @ W1b^T + b1  (64x128), write h, accumulate BN1 stats
// into slot-spread partial arrays (LDS-reduced first: 128 atomics/block).
__global__ __launch_bounds__(256, 3)
void k1_gemm(const float* __restrict__ gout, const float* __restrict__ ss,
             const float* __restrict__ es, const float* __restrict__ W1,
             const float* __restrict__ b1, float* __restrict__ h,
             float* __restrict__ stats1)
{
    __shared__ short As[128 * 40];   // A' tile (128 rows x 32 k), stride 40
    __shared__ short Gs[128 * 40];   // G tile transposed: [d][k], stride 40
    __shared__ short Ps[128 * 128];  // P' bf16, XOR-swizzled 8-elem blocks

    const int bid = blockIdx.x;
    const int b   = bid >> 1;
    const int e0  = (bid & 1) * 64;
    const int t   = threadIdx.x;
    const int w   = t >> 6;
    const int l15 = t & 15;
    const int l4  = (t >> 4) & 3;

    f32x4 acc[2][8];
#pragma unroll
    for (int i = 0; i < 2; ++i)
#pragma unroll
        for (int j = 0; j < 8; ++j) acc[i][j] = f32x4{0.f, 0.f, 0.f, 0.f};

    f32x4 ar[4], gr[4];
    const int arow = t >> 3;        // 0..31, +32p
    const int acol = (t & 7) * 4;   // k-offset within tile
    const int gkr  = t >> 5;        // 0..7, +8p
    const int gcol = (t & 31) * 4;  // d column

    auto load_tiles = [&](int k0) {
#pragma unroll
        for (int p = 0; p < 4; ++p) {
            int row = arow + 32 * p;
            int col = k0 + acol;
            const float* src = (row < 64)
                ? ss + (size_t)(b * EE + e0 + row) * NN + col
                : es + (size_t)(b * EE + e0 + row - 64) * NN + col;
            ar[p] = (col < NN) ? *(const f32x4*)src : f32x4{0.f, 0.f, 0.f, 0.f};
        }
#pragma unroll
        for (int p = 0; p < 4; ++p) {
            int kr = gkr + 8 * p;
            const float* src = gout + (size_t)(b * NN + k0 + kr) * DD + gcol;
            gr[p] = (k0 + kr < NN) ? *(const f32x4*)src : f32x4{0.f, 0.f, 0.f, 0.f};
        }
    };

    auto store_tiles = [&]() {
#pragma unroll
        for (int p = 0; p < 4; ++p) {
            int row = arow + 32 * p;
            bf16x4 v;
            v[0] = f2bf(ar[p][0]); v[1] = f2bf(ar[p][1]);
            v[2] = f2bf(ar[p][2]); v[3] = f2bf(ar[p][3]);
            *(bf16x4*)&As[row * 40 + acol] = v;
        }
#pragma unroll
        for (int p = 0; p < 4; ++p) {
            int kr = gkr + 8 * p;
            Gs[(gcol + 0) * 40 + kr] = f2bf(gr[p][0]);
            Gs[(gcol + 1) * 40 + kr] = f2bf(gr[p][1]);
            Gs[(gcol + 2) * 40 + kr] = f2bf(gr[p][2]);
            Gs[(gcol + 3) * 40 + kr] = f2bf(gr[p][3]);
        }
    };

    load_tiles(0);
    const int NK = (NN + 31) / 32;  // 13
    for (int step = 0; step < NK; ++step) {
        store_tiles();
        __syncthreads();
        if (step + 1 < NK) load_tiles((step + 1) * 32);
        bf16x8 af[2];
#pragma unroll
        for (int rf = 0; rf < 2; ++rf) {
            int row = w * 32 + rf * 16 + l15;
            af[rf] = *(const bf16x8*)&As[row * 40 + l4 * 8];
        }
#pragma unroll
        for (int cf = 0; cf < 8; ++cf) {
            int col = cf * 16 + l15;
            bf16x8 bfr = *(const bf16x8*)&Gs[col * 40 + l4 * 8];
            acc[0][cf] = __builtin_amdgcn_mfma_f32_16x16x32_bf16(af[0], bfr, acc[0][cf], 0, 0, 0);
            acc[1][cf] = __builtin_amdgcn_mfma_f32_16x16x32_bf16(af[1], bfr, acc[1][cf], 0, 0, 0);
        }
        __syncthreads();
    }

    // P' -> LDS bf16, swizzled: off = row*128 + ((col>>3 ^ row&7)*8) + col&7
#pragma unroll
    for (int rf = 0; rf < 2; ++rf)
#pragma unroll
        for (int cf = 0; cf < 8; ++cf)
#pragma unroll
            for (int r = 0; r < 4; ++r) {
                int row = w * 32 + rf * 16 + l4 * 4 + r;
                int col = cf * 16 + l15;
                int off = row * 128 + (((col >> 3) ^ (row & 7)) * 8) + (col & 7);
                Ps[off] = f2bf(acc[rf][cf][r]);
            }
    __syncthreads();

    // Stage 2: h(64x128) = X(64x256) @ W1^T, X from Ps
    f32x4 hacc[4][2];
#pragma unroll
    for (int i = 0; i < 4; ++i) {
        hacc[i][0] = f32x4{0.f, 0.f, 0.f, 0.f};
        hacc[i][1] = f32x4{0.f, 0.f, 0.f, 0.f};
    }
#pragma unroll
    for (int kf = 0; kf < 8; ++kf) {
        const int k0   = kf * 32;
        const int roff = (kf >= 4) ? 64 : 0;
        const int cb   = ((k0 & 127) >> 3) + l4;
        bf16x8 af[4];
#pragma unroll
        for (int rf = 0; rf < 4; ++rf) {
            int row = roff + rf * 16 + l15;
            af[rf] = *(const bf16x8*)&Ps[row * 128 + ((cb ^ (row & 7)) * 8)];
        }
#pragma unroll
        for (int cf = 0; cf < 2; ++cf) {
            int j = w * 32 + cf * 16 + l15;
            const float* wp = W1 + (size_t)j * 256 + k0 + l4 * 8;
            bf16x8 bfr = cvt8(*(const f32x4*)wp, *(const f32x4*)(wp + 4));
#pragma unroll
            for (int rf = 0; rf < 4; ++rf)
                hacc[rf][cf] = __builtin_amdgcn_mfma_f32_16x16x32_bf16(af[rf], bfr, hacc[rf][cf], 0, 0, 0);
        }
    }

    // epilogue: bias, store h, BN1 stats via LDS cross-wave reduce + slot atomics
    float* red = (float*)As;  // 512 floats needed; As is 10 KB, done being read
    const float bj0 = b1[w * 32 + l15];
    const float bj1 = b1[w * 32 + 16 + l15];
    const int j0 = w * 32 + l15;
#pragma unroll
    for (int rf = 0; rf < 4; ++rf) {
        f32x4 v0 = hacc[rf][0] + bj0;
        f32x4 v1 = hacc[rf][1] + bj1;
        int elb = rf * 16 + l4 * 4;
#pragma unroll
        for (int r = 0; r < 4; ++r) {
            float* hp = h + (size_t)(b * EE + e0 + elb + r) * DD;
            hp[j0]      = v0[r];
            hp[j0 + 16] = v1[r];
            float s = v0[r] + v1[r];
            float q = v0[r] * v0[r] + v1[r] * v1[r];
            s += __shfl_xor(s, 1); s += __shfl_xor(s, 2); s += __shfl_xor(s, 4); s += __shfl_xor(s, 8);
            q += __shfl_xor(q, 1); q += __shfl_xor(q, 2); q += __shfl_xor(q, 4); q += __shfl_xor(q, 8);
            if (l15 == 0) {
                red[(elb + r) * 4 + w]       = s;
                red[256 + (elb + r) * 4 + w] = q;
            }
        }
    }
    __syncthreads();
    if (t < 64) {
        float s = red[t * 4] + red[t * 4 + 1] + red[t * 4 + 2] + red[t * 4 + 3];
        float q = red[256 + t * 4] + red[256 + t * 4 + 1] + red[256 + t * 4 + 2] + red[256 + t * 4 + 3];
        int slot = bid & (NSLOT - 1);
        atomicAdd(&stats1[slot * 256 + e0 + t], s);
        atomicAdd(&stats1[slot * 256 + 128 + e0 + t], q);
    }
}

// K3: per b: finalize BN1 (reduce 64 slots), normalize+relu h -> bf16 LDS,
// h2 = X @ W2^T + b2, write h2 to d_out (scratch), accumulate BN2 stats.
__global__ __launch_bounds__(256, 3)
void k3_gemm(const float* __restrict__ h, const float* __restrict__ W2,
             const float* __restrict__ b2, const float* __restrict__ g1,
             const float* __restrict__ bt1, float* __restrict__ out,
             const float* __restrict__ stats1, float* __restrict__ stats2)
{
    __shared__ short Xs[128 * 128];
    __shared__ float sc[128];
    __shared__ float sh[128];
    const int b   = blockIdx.x;
    const int t   = threadIdx.x;
    const int w   = t >> 6;
    const int l15 = t & 15;
    const int l4  = (t >> 4) & 3;

    if (t < 128) {
        float sm = 0.f, sq = 0.f;
#pragma unroll 8
        for (int sl = 0; sl < NSLOT; ++sl) {
            sm += stats1[sl * 256 + t];
            sq += stats1[sl * 256 + 128 + t];
        }
        const float inv_n = 1.0f / (1024.0f * 128.0f);
        float m    = sm * inv_n;
        float var  = sq * inv_n - m * m;
        float rstd = rsqrtf(var + 1e-5f);
        float s    = rstd * g1[t];
        sc[t] = s;
        sh[t] = bt1[t] - m * s;
    }
    __syncthreads();

    {
        const int eb = t >> 5;
        const int c4 = t & 31;
#pragma unroll
        for (int p = 0; p < 16; ++p) {
            int e = eb + 8 * p;
            f32x4 v = *(const f32x4*)(h + (size_t)(b * EE + e) * DD + c4 * 4);
            float s = sc[e], s0 = sh[e];
            bf16x4 o;
#pragma unroll
            for (int i = 0; i < 4; ++i)
                o[i] = f2bf(fmaxf(fmaf(v[i], s, s0), 0.0f));
            int col = c4 * 4;
            int off = e * 128 + (((col >> 3) ^ (e & 7)) * 8) + (col & 7);
            *(bf16x4*)&Xs[off] = o;
        }
    }
    __syncthreads();

    f32x4 acc[8][2];
#pragma unroll
    for (int i = 0; i < 8; ++i) {
        acc[i][0] = f32x4{0.f, 0.f, 0.f, 0.f};
        acc[i][1] = f32x4{0.f, 0.f, 0.f, 0.f};
    }
#pragma unroll
    for (int kf = 0; kf < 4; ++kf) {
        const int k0 = kf * 32;
        const int cb = (k0 >> 3) + l4;
        bf16x8 af[8];
#pragma unroll
        for (int rf = 0; rf < 8; ++rf) {
            int row = rf * 16 + l15;
            af[rf] = *(const bf16x8*)&Xs[row * 128 + ((cb ^ (row & 7)) * 8)];
        }
#pragma unroll
        for (int cf = 0; cf < 2; ++cf) {
            int j = w * 32 + cf * 16 + l15;
            const float* wp = W2 + (size_t)j * 128 + k0 + l4 * 8;
            bf16x8 bfr = cvt8(*(const f32x4*)wp, *(const f32x4*)(wp + 4));
#pragma unroll
            for (int rf = 0; rf < 8; ++rf)
                acc[rf][cf] = __builtin_amdgcn_mfma_f32_16x16x32_bf16(af[rf], bfr, acc[rf][cf], 0, 0, 0);
        }
    }

    __syncthreads();          // all Xs reads done; safe to reuse as reduce buffer
    float* red = (float*)Xs;  // 1024 floats needed
    const float bj0 = b2[w * 32 + l15];
    const float bj1 = b2[w * 32 + 16 + l15];
    const int j0 = w * 32 + l15;
#pragma unroll
    for (int rf = 0; rf < 8; ++rf) {
        f32x4 v0 = acc[rf][0] + bj0;
        f32x4 v1 = acc[rf][1] + bj1;
        int elb = rf * 16 + l4 * 4;
#pragma unroll
        for (int r = 0; r < 4; ++r) {
            float* op = out + (size_t)(b * EE + elb + r) * DD;
            op[j0]      = v0[r];
            op[j0 + 16] = v1[r];
            float s = v0[r] + v1[r];
            float q = v0[r] * v0[r] + v1[r] * v1[r];
            s += __shfl_xor(s, 1); s += __shfl_xor(s, 2); s += __shfl_xor(s, 4); s += __shfl_xor(s, 8);
            q += __shfl_xor(q, 1); q += __shfl_xor(q, 2); q += __shfl_xor(q, 4); q += __shfl_xor(q, 8);
            if (l15 == 0) {
                red[(elb + r) * 4 + w]       = s;
                red[512 + (elb + r) * 4 + w] = q;
            }
        }
    }
    __syncthreads();
    if (t < 128) {
        float s = red[t * 4] + red[t * 4 + 1] + red[t * 4 + 2] + red[t * 4 + 3];
        float q = red[512 + t * 4] + red[512 + t * 4 + 1] + red[512 + t * 4 + 2] + red[512 + t * 4 + 3];
        int slot = b & (NSLOT - 1);
        atomicAdd(&stats2[slot * 256 + t], s);
        atomicAdd(&stats2[slot * 256 + 128 + t], q);
    }
}

// K5: finalize BN2 (reduce 64 slots), out = relu(eout + h2*scale + shift), in-place.
__global__ __launch_bounds__(256)
void k5_final(const float* __restrict__ eout, const float* __restrict__ g2,
              const float* __restrict__ bt2, float* __restrict__ io,
              const float* __restrict__ stats2)
{
    __shared__ float sc[128];
    __shared__ float sh[128];
    const int t = threadIdx.x;
    if (t < 128) {
        float sm = 0.f, sq = 0.f;
#pragma unroll 8
        for (int sl = 0; sl < NSLOT; ++sl) {
            sm += stats2[sl * 256 + t];
            sq += stats2[sl * 256 + 128 + t];
        }
        const float inv_n = 1.0f / (1024.0f * 128.0f);
        float m    = sm * inv_n;
        float var  = sq * inv_n - m * m;
        float rstd = rsqrtf(var + 1e-5f);
        float s    = rstd * g2[t];
        sc[t] = s;
        sh[t] = bt2[t] - m * s;
    }
    __syncthreads();

    const int total4 = BB * EE * DD / 4;
    for (int i4 = blockIdx.x * blockDim.x + t; i4 < total4; i4 += gridDim.x * blockDim.x) {
        int e = (i4 >> 5) & 127;
        f32x4 v = *(f32x4*)(io + (size_t)i4 * 4);
        f32x4 u = *(const f32x4*)(eout + (size_t)i4 * 4);
        float s = sc[e], s0 = sh[e];
        f32x4 o;
#pragma unroll
        for (int i = 0; i < 4; ++i)
            o[i] = fmaxf(u[i] + fmaf(v[i], s, s0), 0.0f);
        *(f32x4*)(io + (size_t)i4 * 4) = o;
    }
}

extern "C" void kernel_launch(void* const* d_in, const int* in_sizes, int n_in,
                              void* d_out, int out_size, void* d_ws, size_t ws_size,
                              hipStream_t stream)
{
    const float* gout  = (const float*)d_in[0];
    const float* eout  = (const float*)d_in[1];
    const float* ss    = (const float*)d_in[2];
    const float* es    = (const float*)d_in[3];
    const float* W1    = (const float*)d_in[4];
    const float* b1    = (const float*)d_in[5];
    const float* W2    = (const float*)d_in[6];
    const float* b2    = (const float*)d_in[7];
    const float* g1    = (const float*)d_in[8];
    const float* bt1   = (const float*)d_in[9];
    const float* g2    = (const float*)d_in[10];
    const float* bt2   = (const float*)d_in[11];

    float* stats1 = (float*)d_ws;                       // [64][256]
    float* stats2 = stats1 + NSLOT * 256;               // [64][256]
    float* h      = stats2 + NSLOT * 256;               // [B][E][D] f32
    float* out    = (float*)d_out;

    hipMemsetAsync((void*)stats1, 0, 2 * NSLOT * 256 * sizeof(float), stream);
    k1_gemm<<<dim3(BB * 2), dim3(256), 0, stream>>>(gout, ss, es, W1, b1, h, stats1);
    k3_gemm<<<dim3(BB), dim3(256), 0, stream>>>(h, W2, b2, g1, bt1, out, stats1, stats2);
    k5_final<<<dim3(2048), dim3(256), 0, stream>>>(eout, g2, bt2, out, stats2);
}

// Round 3
// 257.988 us; speedup vs baseline: 4.0863x; 1.0434x over previous
//
#include <hip/hip_runtime.h>
#include <stdint.h>

#define BB 1024
#define NN 400
#define EE 128
#define DD 128
#define NSLOT 64

typedef float f32x4 __attribute__((ext_vector_type(4)));
typedef float f32x2 __attribute__((ext_vector_type(2)));
typedef short bf16x8 __attribute__((ext_vector_type(8)));
typedef short bf16x4 __attribute__((ext_vector_type(4)));

__device__ __forceinline__ short f2bf(float f) {
    uint32_t u = __builtin_bit_cast(uint32_t, f);
    u += 0x7fffu + ((u >> 16) & 1u);
    return (short)(u >> 16);
}

__device__ __forceinline__ float bf2f(short s) {
    return __builtin_bit_cast(float, (uint32_t)((uint16_t)s) << 16);
}

__device__ __forceinline__ bf16x8 cvt8(const f32x4 a, const f32x4 b) {
    bf16x8 r;
    r[0] = f2bf(a[0]); r[1] = f2bf(a[1]); r[2] = f2bf(a[2]); r[3] = f2bf(a[3]);
    r[4] = f2bf(b[0]); r[5] = f2bf(b[1]); r[6] = f2bf(b[2]); r[7] = f2bf(b[3]);
    return r;
}

// K1: per (b, E-half): P' = [S_half; T_half] @ G  (128x400 @ 400x128), then
// h = Pa @ W1a^T + Pb @ W1b^T + b1  (64x128), write h (bf16), BN1 stats.
// LDS: single 32KB buffer; As/Gs overlay the Ps region (Ps used after K-loop).
__global__ __launch_bounds__(256, 4)
void k1_gemm(const float* __restrict__ gout, const float* __restrict__ ss,
             const float* __restrict__ es, const float* __restrict__ W1,
             const float* __restrict__ b1, unsigned short* __restrict__ h,
             float* __restrict__ stats1)
{
    __shared__ short lds[16384];     // 32 KB
    short* As = lds;                 // [128 rows][40]  (32 k + pad)
    short* Gs = lds + 5120;          // [128 d][40], chunk-XOR swizzled
    short* Ps = lds;                 // [128][128] bf16, used after K-loop

    const int bid = blockIdx.x;
    const int b   = bid >> 1;
    const int e0  = (bid & 1) * 64;
    const int t   = threadIdx.x;
    const int w   = t >> 6;
    const int l15 = t & 15;
    const int l4  = (t >> 4) & 3;

    f32x4 acc[2][8];
#pragma unroll
    for (int i = 0; i < 2; ++i)
#pragma unroll
        for (int j = 0; j < 8; ++j) acc[i][j] = f32x4{0.f, 0.f, 0.f, 0.f};

    // A staging: thread loads 4x f32x4 (rows arow+32p, k acol..acol+3)
    f32x4 ar[4];
    const int arow = t >> 3;        // 0..31
    const int acol = (t & 7) * 4;   // k-offset
    // G staging: thread loads 4 quads (2k x 2d) as f32x2 pairs
    f32x2 g0[4], g1[4];
    const int gx = t & 31;          // d-pair lane
    const int gk = (t >> 5) * 2;    // k-pair base (0..14 even)

    auto load_a = [&](int k0) {
#pragma unroll
        for (int p = 0; p < 4; ++p) {
            int row = arow + 32 * p;
            int col = k0 + acol;
            const float* src = (row < 64)
                ? ss + (size_t)(b * EE + e0 + row) * NN + col
                : es + (size_t)(b * EE + e0 + row - 64) * NN + col;
            ar[p] = (col < NN) ? *(const f32x4*)src : f32x4{0.f, 0.f, 0.f, 0.f};
        }
    };
    auto load_g = [&](int k0) {
#pragma unroll
        for (int p = 0; p < 4; ++p) {
            int d0 = 2 * gx + 64 * (p & 1);
            int k  = k0 + gk + 16 * (p >> 1);
            const float* base = gout + (size_t)b * NN * DD + (size_t)k * DD + d0;
            g0[p] = (k < NN)     ? *(const f32x2*)base        : f32x2{0.f, 0.f};
            g1[p] = (k + 1 < NN) ? *(const f32x2*)(base + DD) : f32x2{0.f, 0.f};
        }
    };
    auto store_a = [&]() {
#pragma unroll
        for (int p = 0; p < 4; ++p) {
            int row = arow + 32 * p;
            bf16x4 v;
            v[0] = f2bf(ar[p][0]); v[1] = f2bf(ar[p][1]);
            v[2] = f2bf(ar[p][2]); v[3] = f2bf(ar[p][3]);
            *(bf16x4*)&As[row * 40 + acol] = v;
        }
    };
    auto store_g = [&]() {
#pragma unroll
        for (int p = 0; p < 4; ++p) {
            int d0 = 2 * gx + 64 * (p & 1);
            int kp = gk + 16 * (p >> 1);
            uint32_t lo = (uint32_t)(uint16_t)f2bf(g0[p][0]) |
                          ((uint32_t)(uint16_t)f2bf(g1[p][0]) << 16);
            uint32_t hi = (uint32_t)(uint16_t)f2bf(g0[p][1]) |
                          ((uint32_t)(uint16_t)f2bf(g1[p][1]) << 16);
            int c  = (kp >> 3) ^ ((d0 >> 2) & 3);   // (d0+1)>>2 == d0>>2 (d0 even)
            int a0 = d0 * 40 + (c << 3) + (kp & 7);
            *(uint32_t*)&Gs[a0]      = lo;
            *(uint32_t*)&Gs[a0 + 40] = hi;
        }
    };

    load_a(0); load_g(0);
    const int NK = (NN + 31) / 32;  // 13
    for (int step = 0; step < NK; ++step) {
        store_a(); store_g();
        __syncthreads();
        if (step + 1 < NK) { load_a((step + 1) * 32); load_g((step + 1) * 32); }
        bf16x8 af[2];
#pragma unroll
        for (int rf = 0; rf < 2; ++rf) {
            int row = w * 32 + rf * 16 + l15;
            af[rf] = *(const bf16x8*)&As[row * 40 + l4 * 8];
        }
#pragma unroll
        for (int cf = 0; cf < 8; ++cf) {
            int col = cf * 16 + l15;
            int cc  = l4 ^ ((col >> 2) & 3);
            bf16x8 bfr = *(const bf16x8*)&Gs[col * 40 + cc * 8];
            acc[0][cf] = __builtin_amdgcn_mfma_f32_16x16x32_bf16(af[0], bfr, acc[0][cf], 0, 0, 0);
            acc[1][cf] = __builtin_amdgcn_mfma_f32_16x16x32_bf16(af[1], bfr, acc[1][cf], 0, 0, 0);
        }
        __syncthreads();
    }

    // P' -> Ps (bf16, XOR-swizzled 8-elem chunks). As/Gs are dead; Ps aliases them.
#pragma unroll
    for (int rf = 0; rf < 2; ++rf)
#pragma unroll
        for (int cf = 0; cf < 8; ++cf)
#pragma unroll
            for (int r = 0; r < 4; ++r) {
                int row = w * 32 + rf * 16 + l4 * 4 + r;
                int col = cf * 16 + l15;
                int off = row * 128 + (((col >> 3) ^ (row & 7)) * 8) + (col & 7);
                Ps[off] = f2bf(acc[rf][cf][r]);
            }
    __syncthreads();

    // Stage 2: h(64x128) = X(64x256) @ W1^T, X from Ps
    f32x4 hacc[4][2];
#pragma unroll
    for (int i = 0; i < 4; ++i) {
        hacc[i][0] = f32x4{0.f, 0.f, 0.f, 0.f};
        hacc[i][1] = f32x4{0.f, 0.f, 0.f, 0.f};
    }
#pragma unroll
    for (int kf = 0; kf < 8; ++kf) {
        const int k0   = kf * 32;
        const int roff = (kf >= 4) ? 64 : 0;
        const int cb   = ((k0 & 127) >> 3) + l4;
        bf16x8 af[4];
#pragma unroll
        for (int rf = 0; rf < 4; ++rf) {
            int row = roff + rf * 16 + l15;
            af[rf] = *(const bf16x8*)&Ps[row * 128 + ((cb ^ (row & 7)) * 8)];
        }
#pragma unroll
        for (int cf = 0; cf < 2; ++cf) {
            int j = w * 32 + cf * 16 + l15;
            const float* wp = W1 + (size_t)j * 256 + k0 + l4 * 8;
            bf16x8 bfr = cvt8(*(const f32x4*)wp, *(const f32x4*)(wp + 4));
#pragma unroll
            for (int rf = 0; rf < 4; ++rf)
                hacc[rf][cf] = __builtin_amdgcn_mfma_f32_16x16x32_bf16(af[rf], bfr, hacc[rf][cf], 0, 0, 0);
        }
    }
    __syncthreads();  // Ps reads done; red aliases Ps

    // epilogue: bias, store h (bf16), BN1 stats via LDS reduce + slot atomics
    float* red = (float*)lds;  // 512 floats
    const float bj0 = b1[w * 32 + l15];
    const float bj1 = b1[w * 32 + 16 + l15];
    const int j0 = w * 32 + l15;
#pragma unroll
    for (int rf = 0; rf < 4; ++rf) {
        f32x4 v0 = hacc[rf][0] + bj0;
        f32x4 v1 = hacc[rf][1] + bj1;
        int elb = rf * 16 + l4 * 4;
#pragma unroll
        for (int r = 0; r < 4; ++r) {
            unsigned short* hp = h + (size_t)(b * EE + e0 + elb + r) * DD;
            hp[j0]      = (unsigned short)f2bf(v0[r]);
            hp[j0 + 16] = (unsigned short)f2bf(v1[r]);
            float s = v0[r] + v1[r];
            float q = v0[r] * v0[r] + v1[r] * v1[r];
            s += __shfl_xor(s, 1); s += __shfl_xor(s, 2); s += __shfl_xor(s, 4); s += __shfl_xor(s, 8);
            q += __shfl_xor(q, 1); q += __shfl_xor(q, 2); q += __shfl_xor(q, 4); q += __shfl_xor(q, 8);
            if (l15 == 0) {
                red[(elb + r) * 4 + w]       = s;
                red[256 + (elb + r) * 4 + w] = q;
            }
        }
    }
    __syncthreads();
    if (t < 64) {
        float s = red[t * 4] + red[t * 4 + 1] + red[t * 4 + 2] + red[t * 4 + 3];
        float q = red[256 + t * 4] + red[256 + t * 4 + 1] + red[256 + t * 4 + 2] + red[256 + t * 4 + 3];
        int slot = bid & (NSLOT - 1);
        atomicAdd(&stats1[slot * 256 + e0 + t], s);
        atomicAdd(&stats1[slot * 256 + 128 + e0 + t], q);
    }
}

// K3: per b: finalize BN1 (reduce slots), normalize+relu h(bf16) -> bf16 LDS,
// h2 = X @ W2^T + b2 -> d_out (f32 scratch), accumulate BN2 stats.
__global__ __launch_bounds__(256, 4)
void k3_gemm(const unsigned short* __restrict__ h, const float* __restrict__ W2,
             const float* __restrict__ b2, const float* __restrict__ g1,
             const float* __restrict__ bt1, float* __restrict__ out,
             const float* __restrict__ stats1, float* __restrict__ stats2)
{
    __shared__ short Xs[128 * 128];
    __shared__ float sc[128];
    __shared__ float sh[128];
    const int b   = blockIdx.x;
    const int t   = threadIdx.x;
    const int w   = t >> 6;
    const int l15 = t & 15;
    const int l4  = (t >> 4) & 3;

    if (t < 128) {
        float sm = 0.f, sq = 0.f;
#pragma unroll 8
        for (int sl = 0; sl < NSLOT; ++sl) {
            sm += stats1[sl * 256 + t];
            sq += stats1[sl * 256 + 128 + t];
        }
        const float inv_n = 1.0f / (1024.0f * 128.0f);
        float m    = sm * inv_n;
        float var  = sq * inv_n - m * m;
        float rstd = rsqrtf(var + 1e-5f);
        float s    = rstd * g1[t];
        sc[t] = s;
        sh[t] = bt1[t] - m * s;
    }
    __syncthreads();

    {
        const int c8 = t & 15;   // 8-col chunk
        const int eb = t >> 4;   // 0..15
#pragma unroll
        for (int p = 0; p < 8; ++p) {
            int e = eb + 16 * p;
            bf16x8 v8 = *(const bf16x8*)&h[((size_t)b * EE + e) * DD + c8 * 8];
            float s = sc[e], s0 = sh[e];
            bf16x8 o;
#pragma unroll
            for (int i = 0; i < 8; ++i)
                o[i] = f2bf(fmaxf(fmaf(bf2f(v8[i]), s, s0), 0.0f));
            *(bf16x8*)&Xs[e * 128 + ((c8 ^ (e & 7)) << 3)] = o;
        }
    }
    __syncthreads();

    f32x4 acc[8][2];
#pragma unroll
    for (int i = 0; i < 8; ++i) {
        acc[i][0] = f32x4{0.f, 0.f, 0.f, 0.f};
        acc[i][1] = f32x4{0.f, 0.f, 0.f, 0.f};
    }
#pragma unroll
    for (int kf = 0; kf < 4; ++kf) {
        const int k0 = kf * 32;
        const int cb = (k0 >> 3) + l4;
        bf16x8 af[8];
#pragma unroll
        for (int rf = 0; rf < 8; ++rf) {
            int row = rf * 16 + l15;
            af[rf] = *(const bf16x8*)&Xs[row * 128 + ((cb ^ (row & 7)) * 8)];
        }
#pragma unroll
        for (int cf = 0; cf < 2; ++cf) {
            int j = w * 32 + cf * 16 + l15;
            const float* wp = W2 + (size_t)j * 128 + k0 + l4 * 8;
            bf16x8 bfr = cvt8(*(const f32x4*)wp, *(const f32x4*)(wp + 4));
#pragma unroll
            for (int rf = 0; rf < 8; ++rf)
                acc[rf][cf] = __builtin_amdgcn_mfma_f32_16x16x32_bf16(af[rf], bfr, acc[rf][cf], 0, 0, 0);
        }
    }

    __syncthreads();
    float* red = (float*)Xs;
    const float bj0 = b2[w * 32 + l15];
    const float bj1 = b2[w * 32 + 16 + l15];
    const int j0 = w * 32 + l15;
#pragma unroll
    for (int rf = 0; rf < 8; ++rf) {
        f32x4 v0 = acc[rf][0] + bj0;
        f32x4 v1 = acc[rf][1] + bj1;
        int elb = rf * 16 + l4 * 4;
#pragma unroll
        for (int r = 0; r < 4; ++r) {
            float* op = out + (size_t)(b * EE + elb + r) * DD;
            op[j0]      = v0[r];
            op[j0 + 16] = v1[r];
            float s = v0[r] + v1[r];
            float q = v0[r] * v0[r] + v1[r] * v1[r];
            s += __shfl_xor(s, 1); s += __shfl_xor(s, 2); s += __shfl_xor(s, 4); s += __shfl_xor(s, 8);
            q += __shfl_xor(q, 1); q += __shfl_xor(q, 2); q += __shfl_xor(q, 4); q += __shfl_xor(q, 8);
            if (l15 == 0) {
                red[(elb + r) * 4 + w]       = s;
                red[512 + (elb + r) * 4 + w] = q;
            }
        }
    }
    __syncthreads();
    if (t < 128) {
        float s = red[t * 4] + red[t * 4 + 1] + red[t * 4 + 2] + red[t * 4 + 3];
        float q = red[512 + t * 4] + red[512 + t * 4 + 1] + red[512 + t * 4 + 2] + red[512 + t * 4 + 3];
        int slot = b & (NSLOT - 1);
        atomicAdd(&stats2[slot * 256 + t], s);
        atomicAdd(&stats2[slot * 256 + 128 + t], q);
    }
}

// K5: finalize BN2, out = relu(eout + h2*scale + shift), in-place on d_out.
__global__ __launch_bounds__(256)
void k5_final(const float* __restrict__ eout, const float* __restrict__ g2,
              const float* __restrict__ bt2, float* __restrict__ io,
              const float* __restrict__ stats2)
{
    __shared__ float sc[128];
    __shared__ float sh[128];
    const int t = threadIdx.x;
    if (t < 128) {
        float sm = 0.f, sq = 0.f;
#pragma unroll 8
        for (int sl = 0; sl < NSLOT; ++sl) {
            sm += stats2[sl * 256 + t];
            sq += stats2[sl * 256 + 128 + t];
        }
        const float inv_n = 1.0f / (1024.0f * 128.0f);
        float m    = sm * inv_n;
        float var  = sq * inv_n - m * m;
        float rstd = rsqrtf(var + 1e-5f);
        float s    = rstd * g2[t];
        sc[t] = s;
        sh[t] = bt2[t] - m * s;
    }
    __syncthreads();

    const int total4 = BB * EE * DD / 4;
    for (int i4 = blockIdx.x * blockDim.x + t; i4 < total4; i4 += gridDim.x * blockDim.x) {
        int e = (i4 >> 5) & 127;
        f32x4 v = *(f32x4*)(io + (size_t)i4 * 4);
        f32x4 u = *(const f32x4*)(eout + (size_t)i4 * 4);
        float s = sc[e], s0 = sh[e];
        f32x4 o;
#pragma unroll
        for (int i = 0; i < 4; ++i)
            o[i] = fmaxf(u[i] + fmaf(v[i], s, s0), 0.0f);
        *(f32x4*)(io + (size_t)i4 * 4) = o;
    }
}

extern "C" void kernel_launch(void* const* d_in, const int* in_sizes, int n_in,
                              void* d_out, int out_size, void* d_ws, size_t ws_size,
                              hipStream_t stream)
{
    const float* gout  = (const float*)d_in[0];
    const float* eout  = (const float*)d_in[1];
    const float* ss    = (const float*)d_in[2];
    const float* es    = (const float*)d_in[3];
    const float* W1    = (const float*)d_in[4];
    const float* b1    = (const float*)d_in[5];
    const float* W2    = (const float*)d_in[6];
    const float* b2    = (const float*)d_in[7];
    const float* g1    = (const float*)d_in[8];
    const float* bt1   = (const float*)d_in[9];
    const float* g2    = (const float*)d_in[10];
    const float* bt2   = (const float*)d_in[11];

    float* stats1 = (float*)d_ws;                       // [64][256]
    float* stats2 = stats1 + NSLOT * 256;               // [64][256]
    unsigned short* h = (unsigned short*)(stats2 + NSLOT * 256);  // [B][E][D] bf16
    float* out    = (float*)d_out;

    hipMemsetAsync((void*)stats1, 0, 2 * NSLOT * 256 * sizeof(float), stream);
    k1_gemm<<<dim3(BB * 2), dim3(256), 0, stream>>>(gout, ss, es, W1, b1, h, stats1);
    k3_gemm<<<dim3(BB), dim3(256), 0, stream>>>(h, W2, b2, g1, bt1, out, stats1, stats2);
    k5_final<<<dim3(2048), dim3(256), 0, stream>>>(eout, g2, bt2, out, stats2);
}